// Round 9
// baseline (27.565 us; speedup 1.0000x reference)
//
#include <hip/hip_runtime.h>
#include <math.h>

// Tropical (min-plus) matmul: out[b, j] = min_i (X[b, i] + W[j, i])
// X: [1024][512] fp32, W: [512][512] fp32, out: [1024][512] fp32.
//
// Round 9: same (b8 x j256 x TN4) geometry as round 8 — provably optimal in
// this family: out-tile b_tile*TN=32 with VMEM ~ 4/b_tile, LDS-reads ~ 4/TN.
// Changes:
//  1. v_pk_add_f32: float2 ext-vector adds + v_min3 -> 1.0 VALU instr per
//     element (was 1.5): per-SIMD VALU 12.3K -> 8.2K cyc.
//  2. De-lockstep: per-wave b-stagger (bb+wid&7)&7 in the LDS *addresses* only
//     (acc stays statically indexed) so the 16 waves' ds_read bursts spread
//     across phases and LDS/VALU overlap instead of alternating.
//  3. part[16][8][lane][4]: one ds_write_b128 per b-row (8 vs 32 writes);
//     W ping-pong in 4-float4 buffers (wA/wB, static) -> ~90 VGPR, headroom
//     for the compiler to pipeline ds_reads.

#define B_DIM   1024
#define IN_DIM  512
#define OUT_DIM 512

typedef float v2f __attribute__((ext_vector_type(2)));

__device__ __forceinline__ v2f mk2(float a, float b) { v2f r; r.x = a; r.y = b; return r; }

// ---------------- prepass: WT4[k4][j] = { W[j][4k4..4k4+3] } ----------------
__global__ __launch_bounds__(256)
void MinPlus_wt4_pack(const float* __restrict__ W, float4* __restrict__ WT4) {
    __shared__ float Ls[64][68];
    const int tid = threadIdx.x;
    const int j0 = blockIdx.x * 64;
    const int k0 = blockIdx.y * 64;

#pragma unroll
    for (int r = 0; r < 4; ++r) {
        const int jj = (tid >> 4) + r * 16;
        const int kq = tid & 15;
        const float4 v = *reinterpret_cast<const float4*>(&W[(j0 + jj) * IN_DIM + k0 + 4 * kq]);
        *reinterpret_cast<float4*>(&Ls[jj][4 * kq]) = v;
    }
    __syncthreads();

    const int jj  = tid & 63;
    const int k4b = tid >> 6;
#pragma unroll
    for (int r = 0; r < 4; ++r) {
        const int k4l = r * 4 + k4b;
        const float4 v = *reinterpret_cast<const float4*>(&Ls[jj][4 * k4l]);
        WT4[(size_t)(blockIdx.y * 16 + k4l) * OUT_DIM + j0 + jj] = v;
    }
}

// ---------------- main ----------------
__global__ __launch_bounds__(1024)
void MinPlus_70832600646269_kernel(const float* __restrict__ X,
                                   const float4* __restrict__ WT4,
                                   float* __restrict__ out)
{
    __shared__ float  Xs[8][IN_DIM];     // 16 KB
    __shared__ float4 part[16][8][64];   // 128 KB: [k-chunk][b][lane] (float4 = 4 jq)

    const int tid  = threadIdx.x;
    const int lane = tid & 63;
    const int wid  = tid >> 6;           // 0..15: k-chunk [32wid, 32wid+32)
    const int j0   = blockIdx.x * 256;
    const int b0   = blockIdx.y * 8;
    const int bs   = wid & 7;            // per-wave b-stagger (de-lockstep)

    // ---- stage X tile: 1024 float4 (16 KB), one per thread, coalesced ----
    reinterpret_cast<float4*>(&Xs[0][0])[tid] =
        reinterpret_cast<const float4*>(X + (size_t)b0 * IN_DIM)[tid];

    // acc: 4 statically-indexed arrays (one per jq); bb is the STATIC index,
    // the runtime b-mapping lives only in LDS addresses (rule: no dyn reg idx).
    float acc0[8], acc1[8], acc2[8], acc3[8];
#pragma unroll
    for (int bb = 0; bb < 8; ++bb)
        acc0[bb] = acc1[bb] = acc2[bb] = acc3[bb] = INFINITY;

    const float4* __restrict__ wbase = WT4 + j0 + lane;
    const int g0 = wid * 8;              // this wave's first k4-group

    float4 wA[4], wB[4];
#pragma unroll
    for (int jq = 0; jq < 4; ++jq)
        wA[jq] = wbase[(size_t)g0 * OUT_DIM + jq * 64];

    __syncthreads();                     // Xs ready

#define COMPUTE(WBUF, G)                                                        \
    {                                                                           \
        const int koff = wid * 32 + (G) * 4;                                    \
        _Pragma("unroll")                                                       \
        for (int bb = 0; bb < 8; ++bb) {                                        \
            const int b = (bb + bs) & 7;                                        \
            const float4 x = *reinterpret_cast<const float4*>(&Xs[b][koff]);    \
            const v2f xlo = mk2(x.x, x.y), xhi = mk2(x.z, x.w);                 \
            const v2f t00 = mk2(WBUF[0].x, WBUF[0].y) + xlo;                    \
            const v2f t01 = mk2(WBUF[0].z, WBUF[0].w) + xhi;                    \
            acc0[bb] = fminf(fminf(acc0[bb], t00.x), t00.y);                    \
            acc0[bb] = fminf(fminf(acc0[bb], t01.x), t01.y);                    \
            const v2f t10 = mk2(WBUF[1].x, WBUF[1].y) + xlo;                    \
            const v2f t11 = mk2(WBUF[1].z, WBUF[1].w) + xhi;                    \
            acc1[bb] = fminf(fminf(acc1[bb], t10.x), t10.y);                    \
            acc1[bb] = fminf(fminf(acc1[bb], t11.x), t11.y);                    \
            const v2f t20 = mk2(WBUF[2].x, WBUF[2].y) + xlo;                    \
            const v2f t21 = mk2(WBUF[2].z, WBUF[2].w) + xhi;                    \
            acc2[bb] = fminf(fminf(acc2[bb], t20.x), t20.y);                    \
            acc2[bb] = fminf(fminf(acc2[bb], t21.x), t21.y);                    \
            const v2f t30 = mk2(WBUF[3].x, WBUF[3].y) + xlo;                    \
            const v2f t31 = mk2(WBUF[3].z, WBUF[3].w) + xhi;                    \
            acc3[bb] = fminf(fminf(acc3[bb], t30.x), t30.y);                    \
            acc3[bb] = fminf(fminf(acc3[bb], t31.x), t31.y);                    \
        }                                                                       \
    }

    // ---- k4-group loop, ping-pong W prefetch (static wA/wB, no dyn index) ----
#pragma unroll 1
    for (int gg = 0; gg < 8; gg += 2) {
#pragma unroll
        for (int jq = 0; jq < 4; ++jq)
            wB[jq] = wbase[(size_t)(g0 + gg + 1) * OUT_DIM + jq * 64];

        COMPUTE(wA, gg)

        if (gg < 6) {
#pragma unroll
            for (int jq = 0; jq < 4; ++jq)
                wA[jq] = wbase[(size_t)(g0 + gg + 2) * OUT_DIM + jq * 64];
        }

        COMPUTE(wB, gg + 1)
    }
#undef COMPUTE

    // ---- per-wave partials: one ds_write_b128 per b-row ----
#pragma unroll
    for (int bb = 0; bb < 8; ++bb) {
        const int b = (bb + bs) & 7;
        part[wid][b][lane] = make_float4(acc0[bb], acc1[bb], acc2[bb], acc3[bb]);
    }

    __syncthreads();

    // ---- combine 16 k-chunks: 512 threads, b128 reads, coalesced b32 stores ----
    if (tid < 512) {
        const int b = tid >> 6;
        const int l = tid & 63;
        float4 m = part[0][b][l];
#pragma unroll
        for (int p = 1; p < 16; ++p) {
            const float4 v = part[p][b][l];
            m.x = fminf(m.x, v.x);
            m.y = fminf(m.y, v.y);
            m.z = fminf(m.z, v.z);
            m.w = fminf(m.w, v.w);
        }
        float* orow = out + (size_t)(b0 + b) * OUT_DIM + j0;
        orow[l]       = m.x;
        orow[64 + l]  = m.y;
        orow[128 + l] = m.z;
        orow[192 + l] = m.w;
    }
}

extern "C" void kernel_launch(void* const* d_in, const int* in_sizes, int n_in,
                              void* d_out, int out_size, void* d_ws, size_t ws_size,
                              hipStream_t stream) {
    const float* X = (const float*)d_in[0];
    const float* W = (const float*)d_in[1];
    float* out = (float*)d_out;
    float4* WT4 = (float4*)d_ws;   // 128 * 512 float4 = 1 MiB

    MinPlus_wt4_pack<<<dim3(OUT_DIM / 64, IN_DIM / 64), 256, 0, stream>>>(W, WT4);

    MinPlus_70832600646269_kernel<<<dim3(OUT_DIM / 256, B_DIM / 8), 1024, 0, stream>>>(X, WT4, out);
}

// Round 10
// 21.963 us; speedup vs baseline: 1.2551x; 1.2551x over previous
//
#include <hip/hip_runtime.h>
#include <math.h>

// Tropical (min-plus) matmul: out[b, j] = min_i (X[b, i] + W[j, i])
// X: [1024][512] fp32, W: [512][512] fp32, out: [1024][512] fp32.
//
// Round 10: dual-pipe X delivery. Geometry b8 x j256 x TN4 (round 8), but:
//  - X rows 0-3 from LDS broadcast ds_read_b128 (512 reads/block = 6.1K cyc)
//  - X rows 4-7 streamed through SGPRs via s_load_dwordx16 (scalar pipe; adds
//    issue as v_add_f32 v,s,v). Round-4-proven asm pattern: issue before the
//    LDS-row compute (768 cyc covers ~300-cyc SMEM latency), tie-based
//    lgkmcnt(0) drain, reuse the same 64 SGPRs per half.
//  - W per 16-k half held in 64 VGPRs (no ping-pong; vmcnt stall at half start
//    is hidden by 4 waves/SIMD). Total ~116 VGPR < 128 cap. NO 2nd
//    __launch_bounds__ arg (round-5 lesson).
//  - Partials: one ds_write_b128/b-row; b128 combine (round-9's good part,
//    WITHOUT the stagger: all LDS addrs compile-time static).
// LDS: Xs[4][512] 8 KB + part[16][8][64]f4 128 KB = 136 KB, 1 block/CU.
// Grid (2 x 128) = 256 blocks = 1/CU, 16 waves/CU, single invocation.

#define B_DIM   1024
#define IN_DIM  512
#define OUT_DIM 512

typedef float f16v __attribute__((ext_vector_type(16)));

// ---------------- prepass: WT4[k4][j] = { W[j][4k4..4k4+3] } ----------------
__global__ __launch_bounds__(256)
void MinPlus_wt4_pack(const float* __restrict__ W, float4* __restrict__ WT4) {
    __shared__ float Ls[64][68];
    const int tid = threadIdx.x;
    const int j0 = blockIdx.x * 64;
    const int k0 = blockIdx.y * 64;

#pragma unroll
    for (int r = 0; r < 4; ++r) {
        const int jj = (tid >> 4) + r * 16;
        const int kq = tid & 15;
        const float4 v = *reinterpret_cast<const float4*>(&W[(j0 + jj) * IN_DIM + k0 + 4 * kq]);
        *reinterpret_cast<float4*>(&Ls[jj][4 * kq]) = v;
    }
    __syncthreads();

    const int jj  = tid & 63;
    const int k4b = tid >> 6;
#pragma unroll
    for (int r = 0; r < 4; ++r) {
        const int k4l = r * 4 + k4b;
        const float4 v = *reinterpret_cast<const float4*>(&Ls[jj][4 * k4l]);
        WT4[(size_t)(blockIdx.y * 16 + k4l) * OUT_DIM + j0 + jj] = v;
    }
}

// ---------------- main ----------------
__global__ __launch_bounds__(1024)
void MinPlus_70832600646269_kernel(const float* __restrict__ X,
                                   const float4* __restrict__ WT4,
                                   float* __restrict__ out)
{
    __shared__ float  Xs[4][IN_DIM];     // 8 KB: X rows b0..b0+3 (LDS-path rows)
    __shared__ float4 part[16][8][64];   // 128 KB: [k-chunk][b][lane]

    const int tid  = threadIdx.x;
    const int lane = tid & 63;
    const int wid  = tid >> 6;           // 0..15: k-chunk [32wid, 32wid+32)
    const int j0   = blockIdx.x * 256;
    const int b0   = blockIdx.y * 8;

    // ---- stage LDS X rows (b0..b0+3): 512 float4, threads 0..511, coalesced ----
    if (tid < 512)
        reinterpret_cast<float4*>(&Xs[0][0])[tid] =
            reinterpret_cast<const float4*>(X + (size_t)b0 * IN_DIM)[tid];

    // ---- SGPR X base: rows b0+4..b0+7, this wave's k-chunk (wave-uniform) ----
    const uint64_t xaddr = (uint64_t)(X + (size_t)(b0 + 4) * IN_DIM + wid * 32);
    const uint32_t xlo = __builtin_amdgcn_readfirstlane((uint32_t)xaddr);
    const uint32_t xhi = __builtin_amdgcn_readfirstlane((uint32_t)(xaddr >> 32));
    const uint64_t sbase = ((uint64_t)xhi << 32) | xlo;

    const float4* __restrict__ wbase = WT4 + j0 + lane;
    const int g0 = wid * 8;              // first k4-group of this wave's chunk

    float accL[4][4], accS[4][4];        // [b][jq], all statically indexed
#pragma unroll
    for (int b = 0; b < 4; ++b)
#pragma unroll
        for (int jq = 0; jq < 4; ++jq) { accL[b][jq] = INFINITY; accS[b][jq] = INFINITY; }

    f16v s0, s1, s2, s3;                 // 64 SGPRs: 4 rows x 16 k (one half)

    __syncthreads();                     // Xs ready

#pragma unroll
    for (int h = 0; h < 2; ++h) {        // two 16-k halves of the 32-k chunk
        // ---- issue SGPR loads for this half (rows 4..7, k-offset h*64 bytes) ----
        if (h == 0) {
            asm volatile("s_load_dwordx16 %0, %4, 0x0\n\t"
                         "s_load_dwordx16 %1, %4, 0x800\n\t"
                         "s_load_dwordx16 %2, %4, 0x1000\n\t"
                         "s_load_dwordx16 %3, %4, 0x1800"
                         : "=&s"(s0), "=&s"(s1), "=&s"(s2), "=&s"(s3) : "s"(sbase));
        } else {
            asm volatile("s_load_dwordx16 %0, %4, 0x40\n\t"
                         "s_load_dwordx16 %1, %4, 0x840\n\t"
                         "s_load_dwordx16 %2, %4, 0x1040\n\t"
                         "s_load_dwordx16 %3, %4, 0x1840"
                         : "=&s"(s0), "=&s"(s1), "=&s"(s2), "=&s"(s3) : "s"(sbase));
        }

        // ---- W for this half: 4 groups x 4 jq = 64 VGPR ----
        float4 w[4][4];
#pragma unroll
        for (int q = 0; q < 4; ++q)
#pragma unroll
            for (int jq = 0; jq < 4; ++jq)
                w[q][jq] = wbase[(size_t)(g0 + h * 4 + q) * OUT_DIM + jq * 64];

        // ---- rows 0-3 from LDS (broadcast b128, static addresses) ----
#pragma unroll
        for (int b = 0; b < 4; ++b) {
#pragma unroll
            for (int q = 0; q < 4; ++q) {
                const float4 x = *reinterpret_cast<const float4*>(
                    &Xs[b][wid * 32 + h * 16 + q * 4]);
#pragma unroll
                for (int jq = 0; jq < 4; ++jq) {
                    const float4 u = w[q][jq];
                    accL[b][jq] = fminf(fminf(accL[b][jq], u.x + x.x), u.y + x.y); // v_min3
                    accL[b][jq] = fminf(fminf(accL[b][jq], u.z + x.z), u.w + x.w); // v_min3
                }
            }
        }

        // ---- drain SMEM (ties order the consumers below) ----
        asm volatile("s_waitcnt lgkmcnt(0)" : "+s"(s0), "+s"(s1), "+s"(s2), "+s"(s3));

        // ---- rows 4-7 from SGPRs (v_add_f32 v,s,v) ----
#pragma unroll
        for (int q = 0; q < 4; ++q) {
#pragma unroll
            for (int jq = 0; jq < 4; ++jq) {
                const float4 u = w[q][jq];
                accS[0][jq] = fminf(fminf(accS[0][jq], u.x + s0[4*q+0]), u.y + s0[4*q+1]);
                accS[0][jq] = fminf(fminf(accS[0][jq], u.z + s0[4*q+2]), u.w + s0[4*q+3]);
                accS[1][jq] = fminf(fminf(accS[1][jq], u.x + s1[4*q+0]), u.y + s1[4*q+1]);
                accS[1][jq] = fminf(fminf(accS[1][jq], u.z + s1[4*q+2]), u.w + s1[4*q+3]);
                accS[2][jq] = fminf(fminf(accS[2][jq], u.x + s2[4*q+0]), u.y + s2[4*q+1]);
                accS[2][jq] = fminf(fminf(accS[2][jq], u.z + s2[4*q+2]), u.w + s2[4*q+3]);
                accS[3][jq] = fminf(fminf(accS[3][jq], u.x + s3[4*q+0]), u.y + s3[4*q+1]);
                accS[3][jq] = fminf(fminf(accS[3][jq], u.z + s3[4*q+2]), u.w + s3[4*q+3]);
            }
        }
    }

    // ---- per-wave partials: one ds_write_b128 per b-row ----
#pragma unroll
    for (int b = 0; b < 4; ++b) {
        part[wid][b][lane]     = make_float4(accL[b][0], accL[b][1], accL[b][2], accL[b][3]);
        part[wid][b + 4][lane] = make_float4(accS[b][0], accS[b][1], accS[b][2], accS[b][3]);
    }

    __syncthreads();

    // ---- combine 16 k-chunks: threads 0..511, b128 reads, coalesced stores ----
    if (tid < 512) {
        const int b = tid >> 6;
        const int l = tid & 63;
        float4 m = part[0][b][l];
#pragma unroll
        for (int p = 1; p < 16; ++p) {
            const float4 v = part[p][b][l];
            m.x = fminf(m.x, v.x);
            m.y = fminf(m.y, v.y);
            m.z = fminf(m.z, v.z);
            m.w = fminf(m.w, v.w);
        }
        float* orow = out + (size_t)(b0 + b) * OUT_DIM + j0;
        orow[l]       = m.x;
        orow[64 + l]  = m.y;
        orow[128 + l] = m.z;
        orow[192 + l] = m.w;
    }
}

extern "C" void kernel_launch(void* const* d_in, const int* in_sizes, int n_in,
                              void* d_out, int out_size, void* d_ws, size_t ws_size,
                              hipStream_t stream) {
    const float* X = (const float*)d_in[0];
    const float* W = (const float*)d_in[1];
    float* out = (float*)d_out;
    float4* WT4 = (float4*)d_ws;   // 128 * 512 float4 = 1 MiB

    MinPlus_wt4_pack<<<dim3(OUT_DIM / 64, IN_DIM / 64), 256, 0, stream>>>(W, WT4);

    MinPlus_70832600646269_kernel<<<dim3(OUT_DIM / 256, B_DIM / 8), 1024, 0, stream>>>(X, WT4, out);
}